// Round 1
// baseline (96.707 us; speedup 1.0000x reference)
//
#include <hip/hip_runtime.h>

#define NBINS 128
#define D_FIXED 512
#define RPB 16  // rows per block in main pass

// ws layout (bytes):
//   [0,512)    int   hist[128]
//   [512,528)  float scal[4]  (T, P, Q)
//   [1024,3072) float u[512]
//   [3072,5120) float v[512]

__global__ __launch_bounds__(1024) void hist_kernel(const int* __restrict__ tgt,
                                                    int n, int* __restrict__ hist) {
    __shared__ int h[NBINS];
    int tid = threadIdx.x;
    if (tid < NBINS) h[tid] = 0;
    __syncthreads();
    for (int i = blockIdx.x * blockDim.x + tid; i < n; i += gridDim.x * blockDim.x)
        atomicAdd(&h[tgt[i] & (NBINS - 1)], 1);
    __syncthreads();
    if (tid < NBINS) {
        int val = h[tid];
        if (val) atomicAdd(&hist[tid], val);
    }
}

__global__ __launch_bounds__(256) void main_pass(const float* __restrict__ x,
                                                 const int* __restrict__ tgt,
                                                 const int* __restrict__ hist,
                                                 int n,
                                                 float* __restrict__ scal,
                                                 float* __restrict__ u,
                                                 float* __restrict__ v) {
    const int half = threadIdx.x >> 7;   // 0 or 1: which row of the pair
    const int j    = threadIdx.x & 127;  // float4 column group (128 * 4 = 512 cols)
    const int r0   = blockIdx.x * RPB;

    float t_acc = 0.f, p_acc = 0.f, q_acc = 0.f;
    float4 ua = make_float4(0.f, 0.f, 0.f, 0.f);
    float4 va = make_float4(0.f, 0.f, 0.f, 0.f);

    for (int it = half; it < RPB; it += 2) {
        int row = r0 + it;
        if (row >= n) break;
        float c = (float)hist[tgt[row] & (NBINS - 1)];
        float4 xv = ((const float4*)(x + (size_t)row * D_FIXED))[j];
        float sq = xv.x * xv.x + xv.y * xv.y + xv.z * xv.z + xv.w * xv.w;
        float sm = xv.x + xv.y + xv.z + xv.w;
        t_acc += sq;
        p_acc += c * sq;
        q_acc += c * sm;
        ua.x += xv.x; ua.y += xv.y; ua.z += xv.z; ua.w += xv.w;
        va.x += c * xv.x; va.y += c * xv.y; va.z += c * xv.z; va.w += c * xv.w;
    }

    // ---- u/v block reduction (two halves own identical columns) ----
    __shared__ float ush[D_FIXED];
    __shared__ float vsh[D_FIXED];
    if (half == 0) {
        ush[4 * j + 0] = ua.x; ush[4 * j + 1] = ua.y;
        ush[4 * j + 2] = ua.z; ush[4 * j + 3] = ua.w;
        vsh[4 * j + 0] = va.x; vsh[4 * j + 1] = va.y;
        vsh[4 * j + 2] = va.z; vsh[4 * j + 3] = va.w;
    }
    __syncthreads();
    if (half == 1) {
        ush[4 * j + 0] += ua.x; ush[4 * j + 1] += ua.y;
        ush[4 * j + 2] += ua.z; ush[4 * j + 3] += ua.w;
        vsh[4 * j + 0] += va.x; vsh[4 * j + 1] += va.y;
        vsh[4 * j + 2] += va.z; vsh[4 * j + 3] += va.w;
    }
    __syncthreads();
    // 256 threads push 512 u entries + 512 v entries (2 each)
    atomicAdd(&u[2 * threadIdx.x + 0], ush[2 * threadIdx.x + 0]);
    atomicAdd(&u[2 * threadIdx.x + 1], ush[2 * threadIdx.x + 1]);
    atomicAdd(&v[2 * threadIdx.x + 0], vsh[2 * threadIdx.x + 0]);
    atomicAdd(&v[2 * threadIdx.x + 1], vsh[2 * threadIdx.x + 1]);

    // ---- scalar (T,P,Q) reduction: wave shuffle then cross-wave LDS ----
    for (int off = 32; off > 0; off >>= 1) {
        t_acc += __shfl_down(t_acc, off);
        p_acc += __shfl_down(p_acc, off);
        q_acc += __shfl_down(q_acc, off);
    }
    __shared__ float red[3][4];
    int wave = threadIdx.x >> 6, lane = threadIdx.x & 63;
    if (lane == 0) { red[0][wave] = t_acc; red[1][wave] = p_acc; red[2][wave] = q_acc; }
    __syncthreads();
    if (threadIdx.x == 0) {
        float t = red[0][0] + red[0][1] + red[0][2] + red[0][3];
        float p = red[1][0] + red[1][1] + red[1][2] + red[1][3];
        float q = red[2][0] + red[2][1] + red[2][2] + red[2][3];
        atomicAdd(&scal[0], t);
        atomicAdd(&scal[1], p);
        atomicAdd(&scal[2], q);
    }
}

__global__ __launch_bounds__(512) void final_kernel(const int* __restrict__ hist,
                                                    const float* __restrict__ scal,
                                                    const float* __restrict__ u,
                                                    const float* __restrict__ v,
                                                    int n, int d,
                                                    float* __restrict__ out) {
    int tid = threadIdx.x;
    float uf = u[tid], vf = v[tid];
    float uu = uf * uf;
    float us = uf;
    float uv = uf * vf;
    float wc = 0.f;
    if (tid < NBINS) {
        float h = (float)hist[tid];
        wc = h * h;  // integers < 2^24: exact in fp32
    }
    for (int off = 32; off > 0; off >>= 1) {
        uu += __shfl_down(uu, off);
        us += __shfl_down(us, off);
        uv += __shfl_down(uv, off);
        wc += __shfl_down(wc, off);
    }
    __shared__ float red[4][8];
    int wave = tid >> 6, lane = tid & 63;
    if (lane == 0) { red[0][wave] = uu; red[1][wave] = us; red[2][wave] = uv; red[3][wave] = wc; }
    __syncthreads();
    if (tid == 0) {
        double UU = 0, US = 0, UV = 0, WC = 0;
        for (int w = 0; w < 8; ++w) {
            UU += red[0][w]; US += red[1][w]; UV += red[2][w]; WC += red[3][w];
        }
        const double T = scal[0], P = scal[1], Q = scal[2];
        const double N = (double)n, Dd = (double)d, eps = 1e-6;
        // Sum_i S_i and Sum_i c_i*S_i from the closed form
        double Ssum = 2.0 * N * T - 2.0 * UU + N * N * Dd * eps * eps;
        double Anum = N * P + T * WC - 2.0 * UV
                    + 2.0 * eps * (N * Q - US * WC) + N * Dd * eps * eps * WC;
        double Wd = N * N - WC;
        double a = Anum / (N * WC);
        double Bnum = N * Ssum - Anum;
        double b = Bnum / (N * Wd);
        out[0] = (float)(-a / b - b / a);
    }
}

extern "C" void kernel_launch(void* const* d_in, const int* in_sizes, int n_in,
                              void* d_out, int out_size, void* d_ws, size_t ws_size,
                              hipStream_t stream) {
    const float* x   = (const float*)d_in[0];
    const int*   tgt = (const int*)d_in[1];
    float*       out = (float*)d_out;

    const int n = in_sizes[1];              // 8192
    const int d = in_sizes[0] / n;          // 512

    char* ws   = (char*)d_ws;
    int*   hist = (int*)ws;                 // 128 ints
    float* scal = (float*)(ws + 512);       // T, P, Q
    float* u    = (float*)(ws + 1024);      // 512 floats
    float* v    = (float*)(ws + 3072);      // 512 floats

    // zero hist + scal + u + v (ws is poisoned 0xAA before every timed call)
    hipMemsetAsync(d_ws, 0, 5120, stream);

    hist_kernel<<<8, 1024, 0, stream>>>(tgt, n, hist);

    int blocks = (n + RPB - 1) / RPB;       // 512 blocks at n=8192
    main_pass<<<blocks, 256, 0, stream>>>(x, tgt, hist, n, scal, u, v);

    final_kernel<<<1, 512, 0, stream>>>(hist, scal, u, v, n, d, out);
}